// Round 4
// baseline (786.245 us; speedup 1.0000x reference)
//
#include <hip/hip_runtime.h>
#include <stdint.h>
#include <stddef.h>

#define AS1 __attribute__((address_space(1)))
#define AS3 __attribute__((address_space(3)))

typedef __attribute__((ext_vector_type(4))) float f32x4;
typedef __attribute__((ext_vector_type(8))) short bf16x8;

static __device__ __forceinline__ unsigned short f2b(float x) {
  union { float f; uint32_t u; } c; c.f = x;
  return (unsigned short)((c.u + 0x7FFFu + ((c.u >> 16) & 1u)) >> 16);
}
static __device__ __forceinline__ float fsig(float x) {
  return __builtin_amdgcn_rcpf(1.f + __expf(-x));
}
static __device__ __forceinline__ float ftanh(float x) {
  return 1.f - 2.f * __builtin_amdgcn_rcpf(__expf(2.f * x) + 1.f);
}

// ---------------- prep kernels ----------------

__global__ __launch_bounds__(256) void k_cvt_bf16(const float* __restrict__ s,
                                                  unsigned short* __restrict__ d,
                                                  int n4) {
  int i = blockIdx.x * 256 + threadIdx.x;
  int stride = gridDim.x * 256;
  for (; i < n4; i += stride) {
    float4 v = ((const float4*)s)[i];
    ushort4 o;
    o.x = f2b(v.x); o.y = f2b(v.y); o.z = f2b(v.z); o.w = f2b(v.w);
    ((ushort4*)d)[i] = o;
  }
}

// row-permuted f32->bf16: permuted row rp = w*64 + q*16 + j  <-  src row q*512 + w*16 + j
__global__ __launch_bounds__(128) void k_cvt_perm(const float* __restrict__ s,
                                                  unsigned short* __restrict__ d) {
  int rp = blockIdx.x;
  int w = rp >> 6, q = (rp >> 4) & 3, j = rp & 15;
  int rs = q * 512 + w * 16 + j;
  float4 v = ((const float4*)(s + (size_t)rs * 512))[threadIdx.x];
  ushort4 o;
  o.x = f2b(v.x); o.y = f2b(v.y); o.z = f2b(v.z); o.w = f2b(v.w);
  ((ushort4*)(d + (size_t)rp * 512))[threadIdx.x] = o;
}

__global__ __launch_bounds__(256) void k_bias_perm(const float* __restrict__ a,
                                                   const float* __restrict__ b,
                                                   float* __restrict__ o) {
  int rp = blockIdx.x * 256 + threadIdx.x;
  if (rp < 2048) {
    int w = rp >> 6, q = (rp >> 4) & 3, j = rp & 15;
    int rs = q * 512 + w * 16 + j;
    o[rp] = a[rs] + b[rs];
  }
}

// row m = t*16+b  <-  emb[xs[b][t]]  (bf16)
__global__ __launch_bounds__(128) void k_emb_gather(const int* __restrict__ xs,
                                                    const float* __restrict__ emb,
                                                    unsigned short* __restrict__ out) {
  int m = blockIdx.x;
  int tok = xs[(m & 15) * 128 + (m >> 4)];
  float4 v = ((const float4*)(emb + (size_t)tok * 512))[threadIdx.x];
  ushort4 o;
  o.x = f2b(v.x); o.y = f2b(v.y); o.z = f2b(v.z); o.w = f2b(v.w);
  ((ushort4*)(out + (size_t)m * 512))[threadIdx.x] = o;
}

// ---------------- bf16 GEMM, B^T layout (m97-style) ----------------
__global__ __launch_bounds__(256) void k_gemm_bt(const unsigned short* __restrict__ A,
                                                 const unsigned short* __restrict__ Bt,
                                                 const float* __restrict__ bias,
                                                 float* __restrict__ C,
                                                 int M, int N, int K) {
  __shared__ unsigned short As[128 * 32];
  __shared__ unsigned short Bs[128 * 32];
  const int tiles_n = N >> 7;
  const int tm = blockIdx.x / tiles_n;
  const int tn = blockIdx.x % tiles_n;
  const int m0 = tm << 7, n0 = tn << 7;
  const int tid = threadIdx.x;
  const int wave = tid >> 6, lane = tid & 63;
  const int wr = wave >> 1, wc = wave & 1;
  f32x4 acc[4][4] = {};

  const int lo = wave * 2048 + lane * 16;
  for (int k0 = 0; k0 < K; k0 += 32) {
#pragma unroll
    for (int i = 0; i < 2; ++i) {
      int o = lo + i * 1024;
      int row = o >> 6, kb = o & 63;
      __builtin_amdgcn_global_load_lds(
          (const AS1 uint32_t*)((const char*)A + ((size_t)(m0 + row) * K + k0) * 2 + kb),
          (AS3 uint32_t*)((char*)As + wave * 2048 + i * 1024), 16, 0, 0);
    }
#pragma unroll
    for (int i = 0; i < 2; ++i) {
      int o = lo + i * 1024;
      int row = o >> 6, kb = o & 63;
      __builtin_amdgcn_global_load_lds(
          (const AS1 uint32_t*)((const char*)Bt + ((size_t)(n0 + row) * K + k0) * 2 + kb),
          (AS3 uint32_t*)((char*)Bs + wave * 2048 + i * 1024), 16, 0, 0);
    }
    __syncthreads();
    bf16x8 af[4], bfr[4];
    const int lrow = lane & 15;
    const int kb16 = (lane >> 4) * 16;
#pragma unroll
    for (int i = 0; i < 4; ++i)
      af[i] = *(const bf16x8*)((const char*)As + (wr * 64 + i * 16 + lrow) * 64 + kb16);
#pragma unroll
    for (int j = 0; j < 4; ++j)
      bfr[j] = *(const bf16x8*)((const char*)Bs + (wc * 64 + j * 16 + lrow) * 64 + kb16);
#pragma unroll
    for (int i = 0; i < 4; ++i)
#pragma unroll
      for (int j = 0; j < 4; ++j)
        acc[i][j] = __builtin_amdgcn_mfma_f32_16x16x32_bf16(af[i], bfr[j], acc[i][j], 0, 0, 0);
    __syncthreads();
  }
#pragma unroll
  for (int j = 0; j < 4; ++j) {
    int col = n0 + wc * 64 + j * 16 + (lane & 15);
    float bv = bias[col];
#pragma unroll
    for (int i = 0; i < 4; ++i) {
      int r0 = m0 + wr * 64 + i * 16 + (lane >> 4) * 4;
#pragma unroll
      for (int r = 0; r < 4; ++r)
        C[(size_t)(r0 + r) * N + col] = acc[i][j][r] + bv;
    }
  }
}

// ---------------- MFMA LSTM: 32 WGs x 1 wave, W in VGPRs, h via IF$ ----------------
// hsb: [129][16][512] bf16. slot 0 = enc_h; step t reads slot t, writes t+1.
// Slots 1..128 pre-filled with 0xFFFF (bf16 NaN sentinel; h=o*tanh(c) is finite).
// Incremental poll: wave-uniform `rem` bitmask of pending k-slices; each pass
// batch-issues loads for pending slices only, then fires that slice's 4 MFMAs
// the moment it validates. Detection overlaps compute; straggler passes load
// only what's missing.

__global__ __launch_bounds__(64, 1) void k_lstm(const float* __restrict__ gp,
                                                const unsigned short* __restrict__ wp,
                                                const float* __restrict__ encc,
                                                unsigned short* __restrict__ hsb) {
  const int wg = blockIdx.x;   // 0..31
  const int l = threadIdx.x;   // 0..63
  const int lr = l & 15;       // n-col within tile / A batch row
  const int lk = l >> 4;       // k-slice quarter (16B)
  const int col = wg * 16 + lr;

  // W_hh fragments, resident in VGPR/AGPR file for the whole kernel
  bf16x8 bfr[4][16];
#pragma unroll
  for (int j = 0; j < 4; ++j)
#pragma unroll
    for (int ks = 0; ks < 16; ++ks)
      bfr[j][ks] = *(const bf16x8*)((const char*)wp +
          (size_t)(wg * 64 + j * 16 + lr) * 1024 + ks * 64 + lk * 16);

  // c-state: 4 batches (lk*4+r) x col, f32, in-lane
  float cst[4];
#pragma unroll
  for (int r = 0; r < 4; ++r) cst[r] = encc[(lk * 4 + r) * 512 + col];

  const uint64_t K1 = 0x0001000100010001ull;
  const uint64_t K8 = 0x8000800080008000ull;
  const int u64off = lr * 128 + lk * 2;  // lane's base u64 index within a slot

  // pre-gates double buffer: prefetch step 0
  float gpre[4][4];
#pragma unroll
  for (int j = 0; j < 4; ++j)
#pragma unroll
    for (int r = 0; r < 4; ++r)
      gpre[j][r] = gp[(size_t)(lk * 4 + r) * 2048 + wg * 64 + j * 16 + lr];

  for (int t = 0; t < 128; ++t) {
    f32x4 acc[4];
#pragma unroll
    for (int j = 0; j < 4; ++j)
#pragma unroll
      for (int r = 0; r < 4; ++r) acc[j][r] = gpre[j][r];
    if (t < 127) {
#pragma unroll
      for (int j = 0; j < 4; ++j)
#pragma unroll
        for (int r = 0; r < 4; ++r)
          gpre[j][r] = gp[(size_t)((t + 1) * 16 + lk * 4 + r) * 2048 +
                          wg * 64 + j * 16 + lr];
    }

    uint64_t* hb = (uint64_t*)(hsb + (size_t)t * 8192);
    uint32_t rem = 0xFFFFu;  // pending k-slices (wave-uniform)
    int guard = 0;
    for (;;) {
      uint64_t a0[16], a1[16];
      // batch-issue loads for pending slices (one latency for all)
#pragma unroll
      for (int ks = 0; ks < 16; ++ks)
        if (rem & (1u << ks)) {
          a0[ks] = __hip_atomic_load(hb + u64off + ks * 8, __ATOMIC_RELAXED,
                                     __HIP_MEMORY_SCOPE_AGENT);
          a1[ks] = __hip_atomic_load(hb + u64off + ks * 8 + 1, __ATOMIC_RELAXED,
                                     __HIP_MEMORY_SCOPE_AGENT);
        }
      // validate + eagerly fire MFMAs per slice
#pragma unroll
      for (int ks = 0; ks < 16; ++ks)
        if (rem & (1u << ks)) {
          uint64_t bad = ((~a0[ks] - K1) & a0[ks] & K8) |
                         ((~a1[ks] - K1) & a1[ks] & K8);
          if (__all(bad == 0)) {
            union { uint64_t q[2]; bf16x8 v; } u;
            u.q[0] = a0[ks]; u.q[1] = a1[ks];
#pragma unroll
            for (int j = 0; j < 4; ++j)
              acc[j] = __builtin_amdgcn_mfma_f32_16x16x32_bf16(u.v, bfr[j][ks],
                                                               acc[j], 0, 0, 0);
            rem &= ~(1u << ks);
          }
        }
      if (rem == 0) break;
      if (++guard > (1 << 20)) break;  // tripwire: wrong, not hung
    }

    // in-lane LSTM cell for 4 (batch, col) pairs; pack col pairs -> u32 store
    unsigned short* hout = hsb + (size_t)(t + 1) * 8192;
#pragma unroll
    for (int r = 0; r < 4; ++r) {
      float iv = fsig(acc[0][r]);
      float fv = fsig(acc[1][r]);
      float gv = ftanh(acc[2][r]);
      float ov = fsig(acc[3][r]);
      cst[r] = fv * cst[r] + iv * gv;
      float hv = ov * ftanh(cst[r]);
      uint32_t mine = f2b(hv);
      uint32_t other = (uint32_t)__shfl_xor((int)mine, 1);
      if ((lr & 1) == 0) {
        uint32_t pk = mine | (other << 16);
        __hip_atomic_store((uint32_t*)(hout + (lk * 4 + r) * 512 + col), pk,
                           __ATOMIC_RELAXED, __HIP_MEMORY_SCOPE_AGENT);
      }
    }
  }
}

// ---------------- launch ----------------

extern "C" void kernel_launch(void* const* d_in, const int* in_sizes, int n_in,
                              void* d_out, int out_size, void* d_ws, size_t ws_size,
                              hipStream_t stream) {
  (void)in_sizes; (void)n_in; (void)out_size; (void)ws_size;
  const int* xs = (const int*)d_in[0];
  const float* ench = (const float*)d_in[2];
  const float* encc = (const float*)d_in[3];
  const float* emb  = (const float*)d_in[4];
  const float* Wih  = (const float*)d_in[5];
  const float* Whh  = (const float*)d_in[6];
  const float* bih  = (const float*)d_in[7];
  const float* bhh  = (const float*)d_in[8];
  const float* Wout = (const float*)d_in[9];
  const float* bout = (const float*)d_in[10];
  float* out = (float*)d_out;

  char* ws = (char*)d_ws;
  size_t off = 0;
  auto take = [&](size_t bytes) {
    char* p = ws + off;
    off += (bytes + 255) & ~(size_t)255;
    return p;
  };
  float* gates_pre      = (float*)take(2048ull * 2048 * 4);        // [T*B][4H] permuted cols
  unsigned short* hsb   = (unsigned short*)take(129ull * 16 * 512 * 2);  // h states bf16
  unsigned short* aemb  = (unsigned short*)take(2048ull * 512 * 2);
  unsigned short* wih_b = (unsigned short*)take(2048ull * 512 * 2);      // permuted rows
  unsigned short* wp_b  = (unsigned short*)take(2048ull * 512 * 2);      // permuted W_hh
  unsigned short* wout_b= (unsigned short*)take(32000ull * 512 * 2);
  float* bias1          = (float*)take(2048 * 4);                        // permuted

  k_cvt_perm<<<2048, 128, 0, stream>>>(Wih, wih_b);
  k_cvt_perm<<<2048, 128, 0, stream>>>(Whh, wp_b);
  k_cvt_bf16<<<2048, 256, 0, stream>>>(Wout, wout_b, 32000 * 512 / 4);
  k_emb_gather<<<2048, 128, 0, stream>>>(xs, emb, aemb);
  k_bias_perm<<<8, 256, 0, stream>>>(bih, bhh, bias1);

  // slot 0 = enc_h (bf16); slots 1..128 = sentinel
  k_cvt_bf16<<<2, 256, 0, stream>>>(ench, hsb, 16 * 512 / 4);
  hipMemsetAsync(hsb + 16 * 512, 0xFF, 128ull * 16 * 512 * 2, stream);

  // gates_pre = aemb @ W_ih_perm^T + (b_ih + b_hh)_perm
  k_gemm_bt<<<256, 256, 0, stream>>>(aemb, wih_b, bias1, gates_pre, 2048, 2048, 512);

  k_lstm<<<32, 64, 0, stream>>>(gates_pre, wp_b, encc, hsb);

  // logits = hs @ W_out^T + b_out   (A = slots 1..128)
  k_gemm_bt<<<4000, 256, 0, stream>>>(hsb + 16 * 512, wout_b, bout, out, 2048, 32000, 512);
}

// Round 5
// 496.640 us; speedup vs baseline: 1.5831x; 1.5831x over previous
//
#include <hip/hip_runtime.h>
#include <stdint.h>
#include <stddef.h>

#define AS1 __attribute__((address_space(1)))
#define AS3 __attribute__((address_space(3)))

typedef __attribute__((ext_vector_type(4))) float f32x4;
typedef __attribute__((ext_vector_type(8))) short bf16x8;
typedef __attribute__((ext_vector_type(4))) unsigned int u32x4;

static __device__ __forceinline__ unsigned short f2b(float x) {
  union { float f; uint32_t u; } c; c.f = x;
  return (unsigned short)((c.u + 0x7FFFu + ((c.u >> 16) & 1u)) >> 16);
}
static __device__ __forceinline__ float fsig(float x) {
  return __builtin_amdgcn_rcpf(1.f + __expf(-x));
}
static __device__ __forceinline__ float ftanh(float x) {
  return 1.f - 2.f * __builtin_amdgcn_rcpf(__expf(2.f * x) + 1.f);
}

// ---------------- prep kernels ----------------

__global__ __launch_bounds__(256) void k_cvt_bf16(const float* __restrict__ s,
                                                  unsigned short* __restrict__ d,
                                                  int n4) {
  int i = blockIdx.x * 256 + threadIdx.x;
  int stride = gridDim.x * 256;
  for (; i < n4; i += stride) {
    float4 v = ((const float4*)s)[i];
    ushort4 o;
    o.x = f2b(v.x); o.y = f2b(v.y); o.z = f2b(v.z); o.w = f2b(v.w);
    ((ushort4*)d)[i] = o;
  }
}

// row-permuted f32->bf16: permuted row rp = w*64 + q*16 + j  <-  src row q*512 + w*16 + j
__global__ __launch_bounds__(128) void k_cvt_perm(const float* __restrict__ s,
                                                  unsigned short* __restrict__ d) {
  int rp = blockIdx.x;
  int w = rp >> 6, q = (rp >> 4) & 3, j = rp & 15;
  int rs = q * 512 + w * 16 + j;
  float4 v = ((const float4*)(s + (size_t)rs * 512))[threadIdx.x];
  ushort4 o;
  o.x = f2b(v.x); o.y = f2b(v.y); o.z = f2b(v.z); o.w = f2b(v.w);
  ((ushort4*)(d + (size_t)rp * 512))[threadIdx.x] = o;
}

__global__ __launch_bounds__(256) void k_bias_perm(const float* __restrict__ a,
                                                   const float* __restrict__ b,
                                                   float* __restrict__ o) {
  int rp = blockIdx.x * 256 + threadIdx.x;
  if (rp < 2048) {
    int w = rp >> 6, q = (rp >> 4) & 3, j = rp & 15;
    int rs = q * 512 + w * 16 + j;
    o[rp] = a[rs] + b[rs];
  }
}

// row m = t*16+b  <-  emb[xs[b][t]]  (bf16)
__global__ __launch_bounds__(128) void k_emb_gather(const int* __restrict__ xs,
                                                    const float* __restrict__ emb,
                                                    unsigned short* __restrict__ out) {
  int m = blockIdx.x;
  int tok = xs[(m & 15) * 128 + (m >> 4)];
  float4 v = ((const float4*)(emb + (size_t)tok * 512))[threadIdx.x];
  ushort4 o;
  o.x = f2b(v.x); o.y = f2b(v.y); o.z = f2b(v.z); o.w = f2b(v.w);
  ((ushort4*)(out + (size_t)m * 512))[threadIdx.x] = o;
}

// ---------------- bf16 GEMM, B^T layout (m97-style) ----------------
__global__ __launch_bounds__(256) void k_gemm_bt(const unsigned short* __restrict__ A,
                                                 const unsigned short* __restrict__ Bt,
                                                 const float* __restrict__ bias,
                                                 float* __restrict__ C,
                                                 int M, int N, int K) {
  __shared__ unsigned short As[128 * 32];
  __shared__ unsigned short Bs[128 * 32];
  const int tiles_n = N >> 7;
  const int tm = blockIdx.x / tiles_n;
  const int tn = blockIdx.x % tiles_n;
  const int m0 = tm << 7, n0 = tn << 7;
  const int tid = threadIdx.x;
  const int wave = tid >> 6, lane = tid & 63;
  const int wr = wave >> 1, wc = wave & 1;
  f32x4 acc[4][4] = {};

  const int lo = wave * 2048 + lane * 16;
  for (int k0 = 0; k0 < K; k0 += 32) {
#pragma unroll
    for (int i = 0; i < 2; ++i) {
      int o = lo + i * 1024;
      int row = o >> 6, kb = o & 63;
      __builtin_amdgcn_global_load_lds(
          (const AS1 uint32_t*)((const char*)A + ((size_t)(m0 + row) * K + k0) * 2 + kb),
          (AS3 uint32_t*)((char*)As + wave * 2048 + i * 1024), 16, 0, 0);
    }
#pragma unroll
    for (int i = 0; i < 2; ++i) {
      int o = lo + i * 1024;
      int row = o >> 6, kb = o & 63;
      __builtin_amdgcn_global_load_lds(
          (const AS1 uint32_t*)((const char*)Bt + ((size_t)(n0 + row) * K + k0) * 2 + kb),
          (AS3 uint32_t*)((char*)Bs + wave * 2048 + i * 1024), 16, 0, 0);
    }
    __syncthreads();
    bf16x8 af[4], bfr[4];
    const int lrow = lane & 15;
    const int kb16 = (lane >> 4) * 16;
#pragma unroll
    for (int i = 0; i < 4; ++i)
      af[i] = *(const bf16x8*)((const char*)As + (wr * 64 + i * 16 + lrow) * 64 + kb16);
#pragma unroll
    for (int j = 0; j < 4; ++j)
      bfr[j] = *(const bf16x8*)((const char*)Bs + (wc * 64 + j * 16 + lrow) * 64 + kb16);
#pragma unroll
    for (int i = 0; i < 4; ++i)
#pragma unroll
      for (int j = 0; j < 4; ++j)
        acc[i][j] = __builtin_amdgcn_mfma_f32_16x16x32_bf16(af[i], bfr[j], acc[i][j], 0, 0, 0);
    __syncthreads();
  }
#pragma unroll
  for (int j = 0; j < 4; ++j) {
    int col = n0 + wc * 64 + j * 16 + (lane & 15);
    float bv = bias[col];
#pragma unroll
    for (int i = 0; i < 4; ++i) {
      int r0 = m0 + wr * 64 + i * 16 + (lane >> 4) * 4;
#pragma unroll
      for (int r = 0; r < 4; ++r)
        C[(size_t)(r0 + r) * N + col] = acc[i][j][r] + bv;
    }
  }
}

// ---------------- MFMA LSTM: 32 same-XCD workers, L2-coherent exchange ----------------
// 256 WGs launched; each reads its hardware XCC_ID and joins a per-XCD ticket
// count. First XCD to reach 32 WGs wins (CAS); its 32 ticket-holders become
// workers, everyone else exits. All workers share one L2, so h-exchange uses
// plain sc0 (L1-bypass) loads/stores: producer stores 8 h-dwords, drains
// vmcnt, sets a flag dword; consumer polls 32 flags with one lane-parallel
// load, then batch-loads 16 A-fragments in one asm block. No agent-scope
// traffic in the hot loop.

__global__ __launch_bounds__(64, 1) void k_lstm(const float* __restrict__ gp,
                                                const unsigned short* __restrict__ wp,
                                                const float* __restrict__ encc,
                                                unsigned short* __restrict__ hsb,
                                                uint32_t* __restrict__ flags,
                                                uint32_t* __restrict__ ctrl) {
  const int l = threadIdx.x;

  // ---- same-XCD election ----
  uint32_t xcc;
  asm volatile("s_getreg_b32 %0, hwreg(HW_REG_XCC_ID)" : "=s"(xcc));
  xcc &= 7u;
  uint32_t ticket = 0;
  if (l == 0) {
    ticket = atomicAdd(&ctrl[xcc], 1u);
    if (ticket == 31u) atomicCAS(&ctrl[8], 0u, xcc + 1u);
  }
  ticket = (uint32_t)__shfl((int)ticket, 0);
  uint32_t win = 0;
  int gd = 0;
  do {
    win = __hip_atomic_load(&ctrl[8], __ATOMIC_RELAXED, __HIP_MEMORY_SCOPE_AGENT);
    if (win) break;
    __builtin_amdgcn_s_sleep(2);
  } while (++gd < (1 << 22));
  if (win != xcc + 1u || ticket >= 32u) return;
  const int w = (int)ticket;  // worker role 0..31 (output is role-symmetric)

  const int lr = l & 15;       // n-col within tile / A batch row
  const int lk = l >> 4;       // k-slice quarter (16B)
  const int col = w * 16 + lr;

  // W_hh fragments, resident in the unified VGPR/AGPR file
  bf16x8 bfr[4][16];
#pragma unroll
  for (int j = 0; j < 4; ++j)
#pragma unroll
    for (int ks = 0; ks < 16; ++ks)
      bfr[j][ks] = *(const bf16x8*)((const char*)wp +
          (size_t)(w * 64 + j * 16 + lr) * 1024 + ks * 64 + lk * 16);

  // c-state: 4 batches (lk*4+r) x col, f32, in-lane
  float cst[4];
#pragma unroll
  for (int r = 0; r < 4; ++r) cst[r] = encc[(lk * 4 + r) * 512 + col];

  // pre-gates double buffer: prefetch step 0
  float gpre[4][4];
#pragma unroll
  for (int j = 0; j < 4; ++j)
#pragma unroll
    for (int r = 0; r < 4; ++r)
      gpre[j][r] = gp[(size_t)(lk * 4 + r) * 2048 + w * 64 + j * 16 + lr];

  for (int t = 0; t < 128; ++t) {
    f32x4 acc[4];
#pragma unroll
    for (int j = 0; j < 4; ++j)
#pragma unroll
      for (int r = 0; r < 4; ++r) acc[j][r] = gpre[j][r];
    if (t < 127) {
#pragma unroll
      for (int j = 0; j < 4; ++j)
#pragma unroll
        for (int r = 0; r < 4; ++r)
          gpre[j][r] = gp[(size_t)((t + 1) * 16 + lk * 4 + r) * 2048 +
                          w * 64 + j * 16 + lr];
    }

    // ---- wait for all 32 producers of slot t (skip at t=0: slot0 = enc_h) ----
    if (t) {
      uint64_t fa = (uint64_t)(uintptr_t)(flags + (size_t)(t - 1) * 32 + (l & 31));
      int guard = 0;
      for (;;) {
        uint32_t fl;
        asm volatile("global_load_dword %0, %1, off sc0\n\ts_waitcnt vmcnt(0)"
                     : "=&v"(fl) : "v"(fa) : "memory");
        if (__all(fl != 0u)) break;
        if (++guard > (1 << 20)) break;  // tripwire: wrong, not hung
      }
    }

    // ---- batch-load 16 A-fragments (one L2 round trip, sc0) ----
    u32x4 q[16];
    {
      uint64_t da = (uint64_t)(uintptr_t)((const char*)hsb +
                    (size_t)t * 16384 + lr * 1024 + lk * 16);
      asm volatile(
          "global_load_dwordx4 %0,  %16, off sc0\n\t"
          "global_load_dwordx4 %1,  %16, off offset:64 sc0\n\t"
          "global_load_dwordx4 %2,  %16, off offset:128 sc0\n\t"
          "global_load_dwordx4 %3,  %16, off offset:192 sc0\n\t"
          "global_load_dwordx4 %4,  %16, off offset:256 sc0\n\t"
          "global_load_dwordx4 %5,  %16, off offset:320 sc0\n\t"
          "global_load_dwordx4 %6,  %16, off offset:384 sc0\n\t"
          "global_load_dwordx4 %7,  %16, off offset:448 sc0\n\t"
          "global_load_dwordx4 %8,  %16, off offset:512 sc0\n\t"
          "global_load_dwordx4 %9,  %16, off offset:576 sc0\n\t"
          "global_load_dwordx4 %10, %16, off offset:640 sc0\n\t"
          "global_load_dwordx4 %11, %16, off offset:704 sc0\n\t"
          "global_load_dwordx4 %12, %16, off offset:768 sc0\n\t"
          "global_load_dwordx4 %13, %16, off offset:832 sc0\n\t"
          "global_load_dwordx4 %14, %16, off offset:896 sc0\n\t"
          "global_load_dwordx4 %15, %16, off offset:960 sc0\n\t"
          "s_waitcnt vmcnt(0)"
          : "=&v"(q[0]), "=&v"(q[1]), "=&v"(q[2]), "=&v"(q[3]),
            "=&v"(q[4]), "=&v"(q[5]), "=&v"(q[6]), "=&v"(q[7]),
            "=&v"(q[8]), "=&v"(q[9]), "=&v"(q[10]), "=&v"(q[11]),
            "=&v"(q[12]), "=&v"(q[13]), "=&v"(q[14]), "=&v"(q[15])
          : "v"(da)
          : "memory");
    }

    // ---- gates = h @ W^T + pre (ks-outer: 4 independent acc chains) ----
#pragma unroll
    for (int ks = 0; ks < 16; ++ks) {
      union { u32x4 q; bf16x8 v; } u;
      u.q = q[ks];
#pragma unroll
      for (int j = 0; j < 4; ++j)
        acc[j] = __builtin_amdgcn_mfma_f32_16x16x32_bf16(u.v, bfr[j][ks],
                                                         acc[j], 0, 0, 0);
    }

    // ---- in-lane LSTM cell; pack col pairs -> dword stores ----
    uint32_t pk[4];
#pragma unroll
    for (int r = 0; r < 4; ++r) {
      float iv = fsig(acc[0][r]);
      float fv = fsig(acc[1][r]);
      float gv = ftanh(acc[2][r]);
      float ov = fsig(acc[3][r]);
      cst[r] = fv * cst[r] + iv * gv;
      float hv = ov * ftanh(cst[r]);
      uint32_t mine = f2b(hv);
      uint32_t other = (uint32_t)__shfl_xor((int)mine, 1);
      pk[r] = mine | (other << 16);
    }
    if ((lr & 1) == 0) {
      uint64_t sa = (uint64_t)(uintptr_t)((char*)hsb +
                    (size_t)(t + 1) * 16384 + lk * 4096 + col * 2);
      asm volatile(
          "global_store_dword %4, %0, off sc0\n\t"
          "global_store_dword %4, %1, off offset:1024 sc0\n\t"
          "global_store_dword %4, %2, off offset:2048 sc0\n\t"
          "global_store_dword %4, %3, off offset:3072 sc0"
          :: "v"(pk[0]), "v"(pk[1]), "v"(pk[2]), "v"(pk[3]), "v"(sa)
          : "memory");
    }
    // release-to-L2: drain this wave's stores, then set our flag
    asm volatile("s_waitcnt vmcnt(0)" ::: "memory");
    if (l == 0) {
      uint32_t one = 1u;
      uint64_t fa2 = (uint64_t)(uintptr_t)(flags + (size_t)t * 32 + w);
      asm volatile("global_store_dword %0, %1, off sc0"
                   :: "v"(fa2), "v"(one) : "memory");
    }
  }
}

// ---------------- launch ----------------

extern "C" void kernel_launch(void* const* d_in, const int* in_sizes, int n_in,
                              void* d_out, int out_size, void* d_ws, size_t ws_size,
                              hipStream_t stream) {
  (void)in_sizes; (void)n_in; (void)out_size; (void)ws_size;
  const int* xs = (const int*)d_in[0];
  const float* ench = (const float*)d_in[2];
  const float* encc = (const float*)d_in[3];
  const float* emb  = (const float*)d_in[4];
  const float* Wih  = (const float*)d_in[5];
  const float* Whh  = (const float*)d_in[6];
  const float* bih  = (const float*)d_in[7];
  const float* bhh  = (const float*)d_in[8];
  const float* Wout = (const float*)d_in[9];
  const float* bout = (const float*)d_in[10];
  float* out = (float*)d_out;

  char* ws = (char*)d_ws;
  size_t off = 0;
  auto take = [&](size_t bytes) {
    char* p = ws + off;
    off += (bytes + 255) & ~(size_t)255;
    return p;
  };
  float* gates_pre      = (float*)take(2048ull * 2048 * 4);        // [T*B][4H] permuted cols
  unsigned short* hsb   = (unsigned short*)take(129ull * 16 * 512 * 2);  // h states bf16
  unsigned short* aemb  = (unsigned short*)take(2048ull * 512 * 2);
  unsigned short* wih_b = (unsigned short*)take(2048ull * 512 * 2);      // permuted rows
  unsigned short* wp_b  = (unsigned short*)take(2048ull * 512 * 2);      // permuted W_hh
  unsigned short* wout_b= (unsigned short*)take(32000ull * 512 * 2);
  float* bias1          = (float*)take(2048 * 4);                        // permuted
  uint32_t* flags       = (uint32_t*)take(128ull * 32 * 4);              // step flags
  uint32_t* ctrl        = (uint32_t*)take(64);                           // election

  k_cvt_perm<<<2048, 128, 0, stream>>>(Wih, wih_b);
  k_cvt_perm<<<2048, 128, 0, stream>>>(Whh, wp_b);
  k_cvt_bf16<<<2048, 256, 0, stream>>>(Wout, wout_b, 32000 * 512 / 4);
  k_emb_gather<<<2048, 128, 0, stream>>>(xs, emb, aemb);
  k_bias_perm<<<8, 256, 0, stream>>>(bih, bhh, bias1);

  // slot 0 = enc_h (bf16)
  k_cvt_bf16<<<2, 256, 0, stream>>>(ench, hsb, 16 * 512 / 4);

  // gates_pre = aemb @ W_ih_perm^T + (b_ih + b_hh)_perm
  k_gemm_bt<<<256, 256, 0, stream>>>(aemb, wih_b, bias1, gates_pre, 2048, 2048, 512);

  hipMemsetAsync(flags, 0, 128ull * 32 * 4, stream);
  hipMemsetAsync(ctrl, 0, 64, stream);
  k_lstm<<<256, 64, 0, stream>>>(gates_pre, wp_b, encc, hsb, flags, ctrl);

  // logits = hs @ W_out^T + b_out   (A = slots 1..128)
  k_gemm_bt<<<4000, 256, 0, stream>>>(hsb + 16 * 512, wout_b, bout, out, 2048, 32000, 512);
}